// Round 6
// baseline (262.022 us; speedup 1.0000x reference)
//
#include <hip/hip_runtime.h>

#define T_DIM 512
#define B_DIM 4096
#define L_DIM 4
#define LOG2E 1.44269504088896f

typedef float f4 __attribute__((ext_vector_type(4)));

// lane(i) <- lane(i-1) within 16-lane DPP rows (row-boundary lanes are l=0,
// which ignore hin: wih=0).
__device__ __forceinline__ float dpp_prev(float v) {
  int r = __builtin_amdgcn_update_dpp(0, __builtin_bit_cast(int, v),
                                      0x111 /*row_shr:1*/, 0xf, 0xf, true);
  return __builtin_bit_cast(float, r);
}
// v += quad_perm(v): one DPP-src add per round; 2 rounds = full quad sum.
template <int CTRL>
__device__ __forceinline__ float qp_add(float v) {
  int r = __builtin_amdgcn_update_dpp(0, __builtin_bit_cast(int, v),
                                      CTRL, 0xf, 0xf, true);
  return v + __builtin_bit_cast(float, r);
}

// Volatile global load: cannot be sunk/dropped; result pinned in VGPRs.
__device__ __forceinline__ void ld_f4(f4& dst, unsigned voff, const f4* base) {
  asm volatile("global_load_dwordx4 %0, %1, %2"
               : "=v"(dst) : "v"(voff), "s"(base) : "memory");
}
// Wait all outstanding VMEM; ring values are in/out so consumers can't hoist.
// Stores are flushed a full chunk (~2000cy) before each wait -> wait is free.
__device__ __forceinline__ void wait_ring(f4* buf) {
  asm volatile("s_waitcnt vmcnt(0)"
               : "+v"(buf[0]), "+v"(buf[1]), "+v"(buf[2]), "+v"(buf[3]),
                 "+v"(buf[4]), "+v"(buf[5]), "+v"(buf[6]), "+v"(buf[7])
               :: "memory");
}

// ---------------- fully fused layer-skewed LSTM ------------------------------
// Lane 4*cb + l: (chain b, layer l) at time t = k - l; h_{l-1}(t) via DPP.
// The layer-0 input GEMV is fused: lane (c,l) loads x[t][c][4l:4l+4] (wave
// reads 1KB contiguous per t) and the quad butterfly produces all 4 gate dots
// in every quad lane (only l=0 consumes, gsel). Weights are pre-scaled by
// -log2e (i,f,o) / +2log2e (g) so gate values feed exp2 directly.
// Activations: sigma(x)=rcp(1+exp2(xs)), tanh=1-2*rcp(1+exp2(xs)); rcps are
// merged pairwise via 1/A = rcp(A*B)*B (8 trans/cell instead of 10).
__global__ __launch_bounds__(64, 1) void lstm_fused(
    const float* __restrict__ x,      // [T,B,16]
    const float* __restrict__ Wih0,   // [4,16]
    const float* __restrict__ Wrest,  // [3,4]
    const float* __restrict__ Whh,    // [4,4]
    const float* __restrict__ bih, const float* __restrict__ bhh,
    float* __restrict__ out) {
  const int lane = threadIdx.x;                    // 0..63
  const int l = lane & 3;                          // layer
  const int b = blockIdx.x * 16 + (lane >> 2);     // chain 0..4095
  const bool l0 = (l == 0);
  const float gsel = l0 ? 1.0f : 0.0f;

  const float sg[4] = {-LOG2E, -LOG2E, 2.0f * LOG2E, -LOG2E};  // gate scales

  float wih[4], whh[4], base[4];
  f4 w4[4];                                        // this lane's Wih0 chunks
#pragma unroll
  for (int g = 0; g < 4; ++g) {
    whh[g]  = sg[g] * Whh[l * 4 + g];
    wih[g]  = l0 ? 0.0f : sg[g] * Wrest[(l - 1) * 4 + g];
    base[g] = sg[g] * (bih[l * 4 + g] + bhh[l * 4 + g]);
    f4 wv = ((const f4*)Wih0)[g * 4 + l];
    w4[g].x = sg[g] * wv.x; w4[g].y = sg[g] * wv.y;
    w4[g].z = sg[g] * wv.z; w4[g].w = sg[g] * wv.w;
  }

  float* __restrict__ po = out + b;
  float h = 0.f, c = 0.f;
  float hsv[8];                                    // chunk's h(l=3) values

  // x addressing: row (t, chain) is 64B; lane offset = lane*16B. Chunk j adds
  // t-stride 4096*64B = 262144B. Wave-uniform chunk base advances via saddr.
  const char* xb = (const char*)x + (size_t)blockIdx.x * 1024;
  unsigned vj[8];
#pragma unroll
  for (int j = 0; j < 8; ++j) vj[j] = (unsigned)lane * 16u + (unsigned)j * 262144u;

  f4 A[8], Bq[8];

  auto load8 = [&](f4* buf, int t0) {
    const f4* p = (const f4*)(xb + (size_t)t0 * 262144);
#pragma unroll
    for (int j = 0; j < 8; ++j) ld_f4(buf[j], vj[j], p);
  };

  auto cell = [&](int k, int j, f4 xv, bool guard) {
    // fused input dots: partials with this lane's 4 x-values, quad butterfly
    float p0 = fmaf(xv.w, w4[0].w, fmaf(xv.z, w4[0].z, fmaf(xv.y, w4[0].y, xv.x * w4[0].x)));
    float p1 = fmaf(xv.w, w4[1].w, fmaf(xv.z, w4[1].z, fmaf(xv.y, w4[1].y, xv.x * w4[1].x)));
    float p2 = fmaf(xv.w, w4[2].w, fmaf(xv.z, w4[2].z, fmaf(xv.y, w4[2].y, xv.x * w4[2].x)));
    float p3 = fmaf(xv.w, w4[3].w, fmaf(xv.z, w4[3].z, fmaf(xv.y, w4[3].y, xv.x * w4[3].x)));
    p0 = qp_add<0x4E>(qp_add<0xB1>(p0));   // xor1 then xor2 -> full quad sum
    p1 = qp_add<0x4E>(qp_add<0xB1>(p1));
    p2 = qp_add<0x4E>(qp_add<0xB1>(p2));
    p3 = qp_add<0x4E>(qp_add<0xB1>(p3));

    float hin = dpp_prev(h);                       // h_{l-1}(t)

    // gates (already exp2-scaled via weight prescale)
    float g0 = fmaf(whh[0], h, fmaf(wih[0], hin, fmaf(gsel, p0, base[0])));
    float g1 = fmaf(whh[1], h, fmaf(wih[1], hin, fmaf(gsel, p1, base[1])));
    float g2 = fmaf(whh[2], h, fmaf(wih[2], hin, fmaf(gsel, p2, base[2])));
    float g3 = fmaf(whh[3], h, fmaf(wih[3], hin, fmaf(gsel, p3, base[3])));

    float Ad = 1.0f + __builtin_amdgcn_exp2f(g0);  // i
    float Bd = 1.0f + __builtin_amdgcn_exp2f(g1);  // f
    float Cd = 1.0f + __builtin_amdgcn_exp2f(g2);  // g (tanh form)
    float Dd = 1.0f + __builtin_amdgcn_exp2f(g3);  // o
    float rAB = __builtin_amdgcn_rcpf(Ad * Bd);
    float rCD = __builtin_amdgcn_rcpf(Cd * Dd);
    float i_ = rAB * Bd;                           // 1/A
    float f_ = rAB * Ad;                           // 1/B
    float tg = fmaf(-2.0f, rCD * Dd, 1.0f);        // tanh = 1 - 2/C
    float o_ = rCD * Cd;                           // 1/D

    float cn  = fmaf(f_, c, i_ * tg);
    float ecn = __builtin_amdgcn_exp2f(2.88539008178f * cn);
    float tcn = fmaf(-2.0f, __builtin_amdgcn_rcpf(1.0f + ecn), 1.0f);
    float hn  = o_ * tcn;

    if (guard) {
      const int t = k - l;
      const bool valid = (unsigned)t < (unsigned)T_DIM;
      c = valid ? cn : c;
      h = valid ? hn : h;
    } else {
      c = cn; h = hn;
    }
    hsv[j] = hn;                                   // l=3 lanes: h_out(t=k-3)
  };
  auto cells8 = [&](int k0, f4* buf, bool guard) {
#pragma unroll
    for (int j = 0; j < 8; ++j) cell(k0 + j, j, buf[j], guard);
  };
  // flush chunk k0's l=3 h-values (t = k0+j-3), j in [jlo,jhi]
  auto flush = [&](int k0, int jlo, int jhi) {
    if (l == 3) {
#pragma unroll
      for (int j = 0; j < 8; ++j)
        if (j >= jlo && j <= jhi)
          po[(size_t)(k0 + j - 3) * B_DIM] = hsv[j];
    }
  };

  load8(A, 0);
  wait_ring(A);
  load8(Bq, 8);
  cells8(0, A, true);                               // warm-up k=0..7
  wait_ring(Bq); flush(0, 3, 7);  load8(A, 16);  cells8(8, Bq, false);
  wait_ring(A);  flush(8, 0, 7);  load8(Bq, 24); cells8(16, A, false);
#pragma unroll 1
  for (int n = 3; n < 63; n += 2) {
    wait_ring(Bq); flush(8 * (n - 1), 0, 7); load8(A, 8 * (n + 1));
    cells8(8 * n, Bq, false);
    wait_ring(A);  flush(8 * n, 0, 7);       load8(Bq, 8 * (n + 2));
    cells8(8 * (n + 1), A, false);
  }
  // chunk 63 (k=504..511):
  wait_ring(Bq); flush(8 * 62, 0, 7);
  cells8(504, Bq, false);
  flush(504, 0, 7);
  // drain chunk (k=512..519): only l>0 lanes still have valid t; Bq is stale
  // but finite, and gsel/guard mask everything invalid.
  cells8(512, Bq, true);
  flush(512, 0, 2);                                 // t=509..511

  // hn, cn: lane (b,l) holds h_l(T-1), c_l(T-1)
  po[(size_t)T_DIM * B_DIM + (size_t)l * B_DIM] = h;
  po[(size_t)T_DIM * B_DIM + (size_t)L_DIM * B_DIM + (size_t)l * B_DIM] = c;
}

extern "C" void kernel_launch(void* const* d_in, const int* in_sizes, int n_in,
                              void* d_out, int out_size, void* d_ws, size_t ws_size,
                              hipStream_t stream) {
  const float* x     = (const float*)d_in[0];
  const float* Wih0  = (const float*)d_in[1];
  const float* Wrest = (const float*)d_in[2];
  const float* Whh   = (const float*)d_in[3];
  const float* bih   = (const float*)d_in[4];
  const float* bhh   = (const float*)d_in[5];
  float* out = (float*)d_out;
  lstm_fused<<<B_DIM / 16, 64, 0, stream>>>(x, Wih0, Wrest, Whh, bih, bhh, out);
}

// Round 8
// 246.263 us; speedup vs baseline: 1.0640x; 1.0640x over previous
//
#include <hip/hip_runtime.h>

#define T_DIM 512
#define B_DIM 4096
#define L_DIM 4
#define LOG2E 1.44269504088896f

typedef float f4 __attribute__((ext_vector_type(4)));

// DPP move with compile-time ctrl (bound_ctrl=1: OOB lanes read 0).
template <int CTRL>
__device__ __forceinline__ float dpp_mov(float v) {
  int r = __builtin_amdgcn_update_dpp(0, __builtin_bit_cast(int, v), CTRL, 0xf, 0xf, true);
  return __builtin_bit_cast(float, r);
}
template <int CTRL>
__device__ __forceinline__ float qp_add(float v) { return v + dpp_mov<CTRL>(v); }

// Volatile global load: cannot be sunk/dropped; result pinned in VGPRs.
__device__ __forceinline__ void ld_f4(f4& dst, unsigned voff, const f4* base) {
  asm volatile("global_load_dwordx4 %0, %1, %2"
               : "=v"(dst) : "v"(voff), "s"(base) : "memory");
}
// Wait for ALL outstanding VMEM (loads and store-acks). Conservative on
// purpose: R6's fine-grained vmcnt(N) over a mixed load/store queue was
// timing-dependent (replay divergence). Ring values are in/out so consumers
// cannot be hoisted above the wait.
__device__ __forceinline__ void wait_ring(f4* buf) {
  asm volatile("s_waitcnt vmcnt(0)"
               : "+v"(buf[0]), "+v"(buf[1]), "+v"(buf[2]), "+v"(buf[3]),
                 "+v"(buf[4]), "+v"(buf[5]), "+v"(buf[6]), "+v"(buf[7])
               :: "memory");
}

// ---------------- gate-split layer-skewed fused LSTM -------------------------
// 65536 threads = 1024 waves (4 waves/CU, one per SIMD).
// lane = 16*c + 4*l + g: block's chain c (4 chains/wave), layer l, gate g.
// Skew: quad (c,l) is at time t = k - l; h_{l-1}(t) arrives via row_shr:4.
// Gates are computed one-per-lane (1 exp2 + 1 rcp each); f,g~,o are gathered
// with 3 quad_perm reads; h is re-broadcast with quad_perm bcast0. Lanes g>0
// carry garbage cs, but it stays finite (f<1 contraction) and never feeds g=0.
// Fused layer-0 GEMV: quad (c,l) computes layer-0 *gate l*'s dot (lane g holds
// x chunk [4g..4g+3] and gate-l weights), quad butterfly sums it, and one
// ds_bpermute routes quad (c,g)'s dot to lane (c,*,g); only l=0 consumes.
// All weights pre-scaled by -log2e (i,f,o) / +2log2e (g~) to feed exp2.
__global__ __launch_bounds__(64, 1) void lstm_fused(
    const float* __restrict__ x,      // [T,B,16]
    const float* __restrict__ Wih0,   // [4,16]
    const float* __restrict__ Wrest,  // [3,4]
    const float* __restrict__ Whh,    // [4,4]
    const float* __restrict__ bih, const float* __restrict__ bhh,
    float* __restrict__ out) {
  const int lane = threadIdx.x;
  const int g = lane & 3;
  const int l = (lane >> 2) & 3;
  const int c = (lane >> 4) & 3;
  const int chain = blockIdx.x * 4 + c;
  const bool l0 = (l == 0);

  const float sgo[4] = {-LOG2E, -LOG2E, 2.0f * LOG2E, -LOG2E};

  // recurrent weights for this lane's (l, g)
  const float whh  = sgo[g] * Whh[l * 4 + g];
  const float wih  = l0 ? 0.f : sgo[g] * Wrest[(l - 1) * 4 + g];
  const float base = l0 ? 0.f : sgo[g] * (bih[l * 4 + g] + bhh[l * 4 + g]);
  // layer-0 GEMV weights: quad (c,l) computes gate l; lane g holds chunk g
  f4 wx;
  {
    const f4 wv = ((const f4*)Wih0)[l * 4 + g];
    const float s = sgo[l];
    wx.x = s * wv.x; wx.y = s * wv.y; wx.z = s * wv.z; wx.w = s * wv.w;
  }
  const float dinit = (g == 0) ? sgo[l] * (bih[l] + bhh[l]) : 0.f;  // bias, once/quad
  const float vm = (g == 2) ? -2.f : 1.f;   // v = r (sigmoid) or 1-2r (tanh)
  const float va = (g == 2) ? 1.f : 0.f;
  const int bperm_addr = 4 * ((lane & 0x30) | (g << 2));  // read quad (c,g) lane 0

  float* __restrict__ po = out + chain;
  float h = 0.f, cs = 0.f;
  float hsv[8];

  // x addressing: t-slice of this block's 4 chains = 256B at xb + t*262144.
  const char* xb = (const char*)x + (size_t)blockIdx.x * 256;
  unsigned vj[8];
#pragma unroll
  for (int j = 0; j < 8; ++j)
    vj[j] = (unsigned)(c * 64 + g * 16) + (unsigned)j * 262144u;

  f4 A[8], Bq[8];

  auto load8 = [&](f4* buf, int t0) {
    const f4* p = (const f4*)(xb + (size_t)t0 * 262144);
#pragma unroll
    for (int j = 0; j < 8; ++j) ld_f4(buf[j], vj[j], p);
  };

  auto cell = [&](int k, int j, f4 xv, bool guard) {
    // layer-0 GEMV: partial dot, quad butterfly, route gate dots to lanes
    float p = fmaf(xv.x, wx.x, fmaf(xv.y, wx.y, fmaf(xv.z, wx.z, fmaf(xv.w, wx.w, dinit))));
    p = qp_add<0xB1>(p);                     // xor1
    p = qp_add<0x4E>(p);                     // xor2 -> full 16-dot in every lane
    float D = __builtin_bit_cast(float,
        __builtin_amdgcn_ds_bpermute(bperm_addr, __builtin_bit_cast(int, p)));

    float hin = dpp_mov<0x114>(h);           // row_shr:4 -> h_{l-1}(t)
    float pb = l0 ? D : base;
    float gate = fmaf(whh, h, fmaf(wih, hin, pb));

    float r = __builtin_amdgcn_rcpf(1.0f + __builtin_amdgcn_exp2f(gate));
    float v = fmaf(vm, r, va);               // lane g: i,f,g~,o respectively

    float f_ = dpp_mov<0x55>(v);             // quad lane1: f
    float tg = dpp_mov<0xAA>(v);             // quad lane2: g~
    float o_ = dpp_mov<0xFF>(v);             // quad lane3: o
    float cn = fmaf(f_, cs, v * tg);         // correct in g=0 (v = i)
    float tcn = fmaf(-2.0f,
        __builtin_amdgcn_rcpf(1.0f + __builtin_amdgcn_exp2f(2.88539008178f * cn)), 1.0f);
    float hm = o_ * tcn;
    float hn = dpp_mov<0x00>(hm);            // bcast g=0's h to the quad

    if (guard) {
      const int t = k - l;
      const bool valid = (unsigned)t < (unsigned)T_DIM;
      cs = valid ? cn : cs;
      h  = valid ? hn : h;
    } else {
      cs = cn; h = hn;
    }
    hsv[j] = hn;
  };
  auto cells8 = [&](int k0, f4* buf, bool guard) {
#pragma unroll
    for (int j = 0; j < 8; ++j) cell(k0 + j, j, buf[j], guard);
  };
  auto flush = [&](int k0, int jlo, int jhi) {
    if (l == 3 && g == 0) {
#pragma unroll
      for (int j = 0; j < 8; ++j)
        if (j >= jlo && j <= jhi) po[(size_t)(k0 + j - 3) * B_DIM] = hsv[j];
    }
  };

  // Schedule (R5-proven): at each chunk top wait vmcnt(0) — everything it
  // drains (prev loads + prev stores) was issued a full cells8 (~1000+ cy)
  // earlier, so the wait is near-free and timing-independent.
  load8(A, 0);
  wait_ring(A);
  load8(Bq, 8);
  cells8(0, A, true);                                    // warm-up k=0..7
  wait_ring(Bq); flush(0, 3, 7);  load8(A, 16);  cells8(8, Bq, false);
  wait_ring(A);  flush(8, 0, 7);  load8(Bq, 24); cells8(16, A, false);
#pragma unroll 1
  for (int n = 3; n < 63; n += 2) {
    wait_ring(Bq); flush(8 * (n - 1), 0, 7); load8(A, 8 * (n + 1));
    cells8(8 * n, Bq, false);
    wait_ring(A);  flush(8 * n, 0, 7);       load8(Bq, 8 * (n + 2));
    cells8(8 * (n + 1), A, false);
  }
  // chunk 63 (k=504..511): Bq was loaded with t=504 in the last loop iter
  wait_ring(Bq); flush(8 * 62, 0, 7);
  cells8(504, Bq, false);
  flush(504, 0, 7);
  // drain (k=512..519): stale-but-finite xv; guard + wih/gsel mask everything
  cells8(512, Bq, true);
  flush(512, 0, 2);                                      // t=509..511

  // hn, cn: every lane of quad (c,l) holds h_l(T-1); g=0 lane holds c_l(T-1)
  if (g == 0) {
    po[(size_t)T_DIM * B_DIM + (size_t)l * B_DIM] = h;
    po[(size_t)T_DIM * B_DIM + (size_t)L_DIM * B_DIM + (size_t)l * B_DIM] = cs;
  }
}

extern "C" void kernel_launch(void* const* d_in, const int* in_sizes, int n_in,
                              void* d_out, int out_size, void* d_ws, size_t ws_size,
                              hipStream_t stream) {
  const float* x     = (const float*)d_in[0];
  const float* Wih0  = (const float*)d_in[1];
  const float* Wrest = (const float*)d_in[2];
  const float* Whh   = (const float*)d_in[3];
  const float* bih   = (const float*)d_in[4];
  const float* bhh   = (const float*)d_in[5];
  float* out = (float*)d_out;
  lstm_fused<<<B_DIM / 4, 64, 0, stream>>>(x, Wih0, Wrest, Whh, bih, bhh, out);
}